// Round 1
// baseline (467.708 us; speedup 1.0000x reference)
//
#include <hip/hip_runtime.h>
#include <math.h>

#define NB   512
#define NPM  8
#define NPH  16
#define NNM  64
#define NNH  64
#define ND   2048
#define TEMP_INV 14.285714285714285714f
#define POSM 0.1f
#define NEGM 0.1f

static constexpr int ROWS_PER_B = NPM + NPH + NNM + NNH;  // 152
static constexpr int NROWBLK    = NB * ROWS_PER_B;        // 77824

// ---------------- block-wide reduction of two floats (256 threads = 4 waves) ---
__device__ __forceinline__ void block_reduce2(float& a, float& b) {
#pragma unroll
  for (int off = 32; off > 0; off >>= 1) {
    a += __shfl_down(a, off);
    b += __shfl_down(b, off);
  }
  __shared__ float sa[4], sb[4];
  const int w = threadIdx.x >> 6;
  if ((threadIdx.x & 63) == 0) { sa[w] = a; sb[w] = b; }
  __syncthreads();
  a = sa[0] + sa[1] + sa[2] + sa[3];
  b = sb[0] + sb[1] + sb[2] + sb[3];
  __syncthreads();  // safe reuse of sa/sb by a later call
}

__device__ __forceinline__ void acc_ss_dot(const float4 v, const float4 u,
                                           float& ss, float& dot) {
  ss  = fmaf(v.x, v.x, ss);  ss  = fmaf(v.y, v.y, ss);
  ss  = fmaf(v.z, v.z, ss);  ss  = fmaf(v.w, v.w, ss);
  dot = fmaf(v.x, u.x, dot); dot = fmaf(v.y, u.y, dot);
  dot = fmaf(v.z, u.z, dot); dot = fmaf(v.w, u.w, dot);
}

// ---------------- k_prep: q_norm, pf_norm, anchor, zero accumulators ----------
__global__ __launch_bounds__(256) void k_prep(const float* __restrict__ q,
                                              const float* __restrict__ pm,
                                              float* __restrict__ qn,
                                              float* __restrict__ pfn,
                                              float* __restrict__ anchor,
                                              float* __restrict__ pos,
                                              float* __restrict__ neg) {
  const int b = blockIdx.x;
  const int t = threadIdx.x;

  // --- normalize q row b ---
  const float4* qrow = (const float4*)(q + (size_t)b * ND);
  float4 q0 = qrow[t];
  float4 q1 = qrow[t + 256];
  float ss = 0.f, dummy = 0.f;
  ss = fmaf(q0.x, q0.x, ss); ss = fmaf(q0.y, q0.y, ss);
  ss = fmaf(q0.z, q0.z, ss); ss = fmaf(q0.w, q0.w, ss);
  ss = fmaf(q1.x, q1.x, ss); ss = fmaf(q1.y, q1.y, ss);
  ss = fmaf(q1.z, q1.z, ss); ss = fmaf(q1.w, q1.w, ss);
  block_reduce2(ss, dummy);
  const float qinv = 1.0f / fmaxf(sqrtf(ss), 1e-8f);
  q0.x *= qinv; q0.y *= qinv; q0.z *= qinv; q0.w *= qinv;
  q1.x *= qinv; q1.y *= qinv; q1.z *= qinv; q1.w *= qinv;
  float4* qno = (float4*)(qn + (size_t)b * ND);
  qno[t] = q0; qno[t + 256] = q1;

  // --- normalize pm[b, 0] and anchor = q_norm . pf_norm ---
  const float4* prow = (const float4*)(pm + (size_t)b * NPM * ND);
  float4 p0 = prow[t];
  float4 p1 = prow[t + 256];
  float pss = 0.f, dot = 0.f;
  acc_ss_dot(p0, q0, pss, dot);
  acc_ss_dot(p1, q1, pss, dot);
  block_reduce2(pss, dot);
  const float pinv = 1.0f / fmaxf(sqrtf(pss), 1e-8f);
  p0.x *= pinv; p0.y *= pinv; p0.z *= pinv; p0.w *= pinv;
  p1.x *= pinv; p1.y *= pinv; p1.z *= pinv; p1.w *= pinv;
  float4* pfo = (float4*)(pfn + (size_t)b * ND);
  pfo[t] = p0; pfo[t + 256] = p1;

  if (t == 0) {
    anchor[b] = dot * pinv;
    pos[b] = 0.f;
    neg[b] = 0.f;
  }
}

// ---------------- k_rows: one block per candidate row ------------------------
__global__ __launch_bounds__(256) void k_rows(const float* __restrict__ pmain,
                                              const float* __restrict__ phard,
                                              const float* __restrict__ nmain,
                                              const float* __restrict__ nhard,
                                              const float* __restrict__ qn,
                                              const float* __restrict__ anchor,
                                              float* __restrict__ pos,
                                              float* __restrict__ neg) {
  const int i = blockIdx.x;
  const int b = i / ROWS_PER_B;
  const int r = i % ROWS_PER_B;

  const float* base;
  int kind;  // 0 = pos_main (unmasked), 1 = pos_hard, 2 = negative
  if (r < NPM) {
    base = pmain + ((size_t)b * NPM + r) * ND; kind = 0;
  } else if (r < NPM + NPH) {
    base = phard + ((size_t)b * NPH + (r - NPM)) * ND; kind = 1;
  } else if (r < NPM + NPH + NNM) {
    base = nmain + ((size_t)b * NNM + (r - NPM - NPH)) * ND; kind = 2;
  } else {
    base = nhard + ((size_t)b * NNH + (r - NPM - NPH - NNM)) * ND; kind = 2;
  }

  const float4* row  = (const float4*)base;
  const float4* qrow = (const float4*)(qn + (size_t)b * ND);
  float ss = 0.f, dot = 0.f;
  const int t = threadIdx.x;
  float4 v0 = row[t],       u0 = qrow[t];
  float4 v1 = row[t + 256], u1 = qrow[t + 256];
  acc_ss_dot(v0, u0, ss, dot);
  acc_ss_dot(v1, u1, ss, dot);
  block_reduce2(ss, dot);

  if (t == 0) {
    const float sim = dot / fmaxf(sqrtf(ss), 1e-8f);
    const float a   = anchor[b];
    const float e   = expf(sim * TEMP_INV);
    if (kind == 0) {
      atomicAdd(pos + b, e);
    } else if (kind == 1) {
      if (sim >= a - POSM) atomicAdd(pos + b, e);
    } else {
      if (sim <= a + NEGM) atomicAdd(neg + b, e);
    }
  }
}

// ---------------- k_gemm: three 512x512 sim matrices, masked exp row-sums -----
// z = 0: q@q^T, z = 1: pf@pf^T, z = 2: q@pf^T. 64x64 tile, 256 threads, 4x4/thread.
__global__ __launch_bounds__(256) void k_gemm(const float* __restrict__ qn,
                                              const float* __restrict__ pfn,
                                              const float* __restrict__ anchor,
                                              float* __restrict__ neg) {
  const int which = blockIdx.z;
  const float* __restrict__ A  = (which == 1) ? pfn : qn;
  const float* __restrict__ Bm = (which == 0) ? qn : pfn;
  const int rb = blockIdx.y * 64;
  const int cb = blockIdx.x * 64;

  __shared__ float As[64][65];  // stride 65 -> <=2-way bank aliasing (free)
  __shared__ float Bs[64][65];

  const int t  = threadIdx.x;
  const int tx = t & 15;
  const int ty = t >> 4;

  float acc[4][4] = {{0.f, 0.f, 0.f, 0.f}, {0.f, 0.f, 0.f, 0.f},
                     {0.f, 0.f, 0.f, 0.f}, {0.f, 0.f, 0.f, 0.f}};

  for (int k0 = 0; k0 < ND; k0 += 64) {
    // load 64x64 tiles: 1024 float4 per tile, 4 per thread
#pragma unroll
    for (int s = 0; s < 4; s++) {
      const int f   = t + s * 256;
      const int row = f >> 4;        // 0..63
      const int c4  = (f & 15) * 4;  // 0..60
      const float4 av = *(const float4*)(A  + (size_t)(rb + row) * ND + k0 + c4);
      const float4 bv = *(const float4*)(Bm + (size_t)(cb + row) * ND + k0 + c4);
      As[row][c4 + 0] = av.x; As[row][c4 + 1] = av.y;
      As[row][c4 + 2] = av.z; As[row][c4 + 3] = av.w;
      Bs[row][c4 + 0] = bv.x; Bs[row][c4 + 1] = bv.y;
      Bs[row][c4 + 2] = bv.z; Bs[row][c4 + 3] = bv.w;
    }
    __syncthreads();

#pragma unroll 8
    for (int k = 0; k < 64; k++) {
      const float a0 = As[ty * 4 + 0][k];
      const float a1 = As[ty * 4 + 1][k];
      const float a2 = As[ty * 4 + 2][k];
      const float a3 = As[ty * 4 + 3][k];
      const float b0 = Bs[tx * 4 + 0][k];
      const float b1 = Bs[tx * 4 + 1][k];
      const float b2 = Bs[tx * 4 + 2][k];
      const float b3 = Bs[tx * 4 + 3][k];
      acc[0][0] = fmaf(a0, b0, acc[0][0]); acc[0][1] = fmaf(a0, b1, acc[0][1]);
      acc[0][2] = fmaf(a0, b2, acc[0][2]); acc[0][3] = fmaf(a0, b3, acc[0][3]);
      acc[1][0] = fmaf(a1, b0, acc[1][0]); acc[1][1] = fmaf(a1, b1, acc[1][1]);
      acc[1][2] = fmaf(a1, b2, acc[1][2]); acc[1][3] = fmaf(a1, b3, acc[1][3]);
      acc[2][0] = fmaf(a2, b0, acc[2][0]); acc[2][1] = fmaf(a2, b1, acc[2][1]);
      acc[2][2] = fmaf(a2, b2, acc[2][2]); acc[2][3] = fmaf(a2, b3, acc[2][3]);
      acc[3][0] = fmaf(a3, b0, acc[3][0]); acc[3][1] = fmaf(a3, b1, acc[3][1]);
      acc[3][2] = fmaf(a3, b2, acc[3][2]); acc[3][3] = fmaf(a3, b3, acc[3][3]);
    }
    __syncthreads();
  }

  // epilogue: masked exp row-sums into neg
#pragma unroll
  for (int i = 0; i < 4; i++) {
    const int gr = rb + ty * 4 + i;
    const float thr = anchor[gr] + NEGM;
    float rsum = 0.f;
#pragma unroll
    for (int j = 0; j < 4; j++) {
      const int gc = cb + tx * 4 + j;
      const float sim = acc[i][j];
      if (gr != gc && sim <= thr) rsum += expf(sim * TEMP_INV);
    }
    atomicAdd(neg + gr, rsum);
  }
}

// ---------------- k_loss: per-b loss, mean ------------------------------------
__global__ __launch_bounds__(512) void k_loss(const float* __restrict__ pos,
                                              const float* __restrict__ neg,
                                              float* __restrict__ out) {
  const int t = threadIdx.x;
  const float p = pos[t];
  const float n = neg[t];
  float l = -logf(p / (p + n + 1e-8f));
#pragma unroll
  for (int off = 32; off > 0; off >>= 1) l += __shfl_down(l, off);
  __shared__ float s[8];
  if ((t & 63) == 0) s[t >> 6] = l;
  __syncthreads();
  if (t == 0) {
    float tot = 0.f;
#pragma unroll
    for (int i = 0; i < 8; i++) tot += s[i];
    out[0] = tot / (float)NB;
  }
}

extern "C" void kernel_launch(void* const* d_in, const int* in_sizes, int n_in,
                              void* d_out, int out_size, void* d_ws, size_t ws_size,
                              hipStream_t stream) {
  const float* q  = (const float*)d_in[0];
  const float* pm = (const float*)d_in[1];
  const float* ph = (const float*)d_in[2];
  const float* nm = (const float*)d_in[3];
  const float* nh = (const float*)d_in[4];
  float* out = (float*)d_out;

  float* ws     = (float*)d_ws;
  float* qn     = ws;                          // 512*2048
  float* pfn    = ws + (size_t)NB * ND;        // 512*2048
  float* anchor = ws + (size_t)2 * NB * ND;    // 512
  float* pos    = anchor + NB;                 // 512
  float* neg    = pos + NB;                    // 512

  k_prep<<<NB, 256, 0, stream>>>(q, pm, qn, pfn, anchor, pos, neg);
  k_rows<<<NROWBLK, 256, 0, stream>>>(pm, ph, nm, nh, qn, anchor, pos, neg);
  k_gemm<<<dim3(8, 8, 3), 256, 0, stream>>>(qn, pfn, anchor, neg);
  k_loss<<<1, 512, 0, stream>>>(pos, neg, out);
}

// Round 2
// 248.081 us; speedup vs baseline: 1.8853x; 1.8853x over previous
//
#include <hip/hip_runtime.h>
#include <math.h>

#define NB   512
#define NPM  8
#define NPH  16
#define NNM  64
#define NNH  64
#define ND   2048
#define TEMP_INV 14.285714285714285714f
#define POSM 0.1f
#define NEGM 0.1f

static constexpr int ROWS_PER_B = NPM + NPH + NNM + NNH;  // 152
static constexpr int NROWS      = NB * ROWS_PER_B;        // 77824

typedef __attribute__((ext_vector_type(8))) short bf16x8;
typedef __attribute__((ext_vector_type(4))) float f32x4;

// round-to-nearest-even f32 -> bf16 bits (inputs are normal floats)
__device__ __forceinline__ unsigned short f2bf(float f) {
  unsigned int u = __float_as_uint(f);
  return (unsigned short)((u + 0x7FFFu + ((u >> 16) & 1u)) >> 16);
}

__device__ __forceinline__ void acc_ss_dot(const float4 v, const float4 u,
                                           float& ss, float& dot) {
  ss  = fmaf(v.x, v.x, ss);  ss  = fmaf(v.y, v.y, ss);
  ss  = fmaf(v.z, v.z, ss);  ss  = fmaf(v.w, v.w, ss);
  dot = fmaf(v.x, u.x, dot); dot = fmaf(v.y, u.y, dot);
  dot = fmaf(v.z, u.z, dot); dot = fmaf(v.w, u.w, dot);
}

__device__ __forceinline__ void block_reduce2(float& a, float& b) {
#pragma unroll
  for (int off = 32; off > 0; off >>= 1) {
    a += __shfl_down(a, off);
    b += __shfl_down(b, off);
  }
  __shared__ float sa[4], sb[4];
  const int w = threadIdx.x >> 6;
  if ((threadIdx.x & 63) == 0) { sa[w] = a; sb[w] = b; }
  __syncthreads();
  a = sa[0] + sa[1] + sa[2] + sa[3];
  b = sb[0] + sb[1] + sb[2] + sb[3];
  __syncthreads();
}

// ---- k_prep: q_norm (f32 + bf16), pf_norm (bf16), anchor, zero accumulators --
__global__ __launch_bounds__(256) void k_prep(const float* __restrict__ q,
                                              const float* __restrict__ pm,
                                              float* __restrict__ qn,
                                              unsigned short* __restrict__ qb,
                                              unsigned short* __restrict__ pb,
                                              float* __restrict__ anchor,
                                              float* __restrict__ pos,
                                              float* __restrict__ neg) {
  const int b = blockIdx.x;
  const int t = threadIdx.x;

  const float4* qrow = (const float4*)(q + (size_t)b * ND);
  float4 q0 = qrow[t];
  float4 q1 = qrow[t + 256];
  float ss = 0.f, dummy = 0.f;
  ss = fmaf(q0.x, q0.x, ss); ss = fmaf(q0.y, q0.y, ss);
  ss = fmaf(q0.z, q0.z, ss); ss = fmaf(q0.w, q0.w, ss);
  ss = fmaf(q1.x, q1.x, ss); ss = fmaf(q1.y, q1.y, ss);
  ss = fmaf(q1.z, q1.z, ss); ss = fmaf(q1.w, q1.w, ss);
  block_reduce2(ss, dummy);
  const float qinv = 1.0f / fmaxf(sqrtf(ss), 1e-8f);
  q0.x *= qinv; q0.y *= qinv; q0.z *= qinv; q0.w *= qinv;
  q1.x *= qinv; q1.y *= qinv; q1.z *= qinv; q1.w *= qinv;
  float4* qno = (float4*)(qn + (size_t)b * ND);
  qno[t] = q0; qno[t + 256] = q1;
  ushort4* qbo = (ushort4*)(qb + (size_t)b * ND);
  ushort4 qc0, qc1;
  qc0.x = f2bf(q0.x); qc0.y = f2bf(q0.y); qc0.z = f2bf(q0.z); qc0.w = f2bf(q0.w);
  qc1.x = f2bf(q1.x); qc1.y = f2bf(q1.y); qc1.z = f2bf(q1.z); qc1.w = f2bf(q1.w);
  qbo[t] = qc0; qbo[t + 256] = qc1;

  const float4* prow = (const float4*)(pm + (size_t)b * NPM * ND);
  float4 p0 = prow[t];
  float4 p1 = prow[t + 256];
  float pss = 0.f, dot = 0.f;
  acc_ss_dot(p0, q0, pss, dot);
  acc_ss_dot(p1, q1, pss, dot);
  block_reduce2(pss, dot);
  const float pinv = 1.0f / fmaxf(sqrtf(pss), 1e-8f);
  p0.x *= pinv; p0.y *= pinv; p0.z *= pinv; p0.w *= pinv;
  p1.x *= pinv; p1.y *= pinv; p1.z *= pinv; p1.w *= pinv;
  ushort4* pbo = (ushort4*)(pb + (size_t)b * ND);
  ushort4 pc0, pc1;
  pc0.x = f2bf(p0.x); pc0.y = f2bf(p0.y); pc0.z = f2bf(p0.z); pc0.w = f2bf(p0.w);
  pc1.x = f2bf(p1.x); pc1.y = f2bf(p1.y); pc1.z = f2bf(p1.z); pc1.w = f2bf(p1.w);
  pbo[t] = pc0; pbo[t + 256] = pc1;

  if (t == 0) {
    anchor[b] = dot * pinv;
    pos[b] = 0.f;
    neg[b] = 0.f;
  }
}

// ---- k_rows: one WAVE per candidate row, shfl-only reduce --------------------
__global__ __launch_bounds__(256) void k_rows(const float* __restrict__ pmain,
                                              const float* __restrict__ phard,
                                              const float* __restrict__ nmain,
                                              const float* __restrict__ nhard,
                                              const float* __restrict__ qn,
                                              const float* __restrict__ anchor,
                                              float* __restrict__ pos,
                                              float* __restrict__ neg) {
  const int w = blockIdx.x * 4 + (threadIdx.x >> 6);  // row id, < 77824
  const int lane = threadIdx.x & 63;
  const int b = w / ROWS_PER_B;
  const int r = w % ROWS_PER_B;

  const float* base;
  int kind;  // 0 = pos_main (unmasked), 1 = pos_hard, 2 = negative
  if (r < NPM) {
    base = pmain + ((size_t)b * NPM + r) * ND; kind = 0;
  } else if (r < NPM + NPH) {
    base = phard + ((size_t)b * NPH + (r - NPM)) * ND; kind = 1;
  } else if (r < NPM + NPH + NNM) {
    base = nmain + ((size_t)b * NNM + (r - NPM - NPH)) * ND; kind = 2;
  } else {
    base = nhard + ((size_t)b * NNH + (r - NPM - NPH - NNM)) * ND; kind = 2;
  }

  const float4* row  = (const float4*)base;
  const float4* qrow = (const float4*)(qn + (size_t)b * ND);
  float ss = 0.f, dot = 0.f;
#pragma unroll
  for (int j = 0; j < 8; j++) {
    const float4 v = row[lane + 64 * j];
    const float4 u = qrow[lane + 64 * j];
    acc_ss_dot(v, u, ss, dot);
  }
#pragma unroll
  for (int off = 32; off > 0; off >>= 1) {
    ss  += __shfl_xor(ss, off);
    dot += __shfl_xor(dot, off);
  }

  if (lane == 0) {
    const float sim = dot / fmaxf(sqrtf(ss), 1e-8f);
    const float a   = anchor[b];
    const float e   = expf(sim * TEMP_INV);
    if (kind == 0) {
      atomicAdd(pos + b, e);
    } else if (kind == 1) {
      if (sim >= a - POSM) atomicAdd(pos + b, e);
    } else {
      if (sim <= a + NEGM) atomicAdd(neg + b, e);
    }
  }
}

// ---- k_sim: three 512x512 sim matrices via bf16 MFMA, masked exp row-sums ----
// z=0: q@q^T, z=1: pf@pf^T, z=2: q@pf^T. One wave = 16x32 output tile.
// Fragment layout (gfx950 mfma_f32_16x16x32_bf16):
//   A/B: lane l holds row/col (l&15), k = (l>>4)*8 + j  (8 bf16 = 4 VGPRs)
//   C/D: col = lane&15, row = (lane>>4)*4 + reg          [m89-verified]
__global__ __launch_bounds__(256) void k_sim(const unsigned short* __restrict__ qb,
                                             const unsigned short* __restrict__ pb,
                                             const float* __restrict__ anchor,
                                             float* __restrict__ neg) {
  const int z = blockIdx.z;
  const unsigned short* __restrict__ A = (z == 1) ? pb : qb;
  const unsigned short* __restrict__ B = (z == 0) ? qb : pb;

  const int wid  = blockIdx.x * 4 + (threadIdx.x >> 6);  // 0..511
  const int m    = wid >> 4;   // row-tile 0..31
  const int n2   = wid & 15;   // col-pair 0..15
  const int lane = threadIdx.x & 63;
  const int r16  = lane & 15;
  const int kc   = lane >> 4;

  const size_t abase  = ((size_t)(m * 16 + r16)) * ND + kc * 8;
  const size_t b0base = ((size_t)(n2 * 32 + r16)) * ND + kc * 8;
  const size_t b1base = b0base + (size_t)16 * ND;

  f32x4 acc0 = {0.f, 0.f, 0.f, 0.f};
  f32x4 acc1 = {0.f, 0.f, 0.f, 0.f};
#pragma unroll 2
  for (int k0 = 0; k0 < ND; k0 += 64) {
    const bf16x8 a0  = *(const bf16x8*)(A + abase  + k0);
    const bf16x8 a1  = *(const bf16x8*)(A + abase  + k0 + 32);
    const bf16x8 b00 = *(const bf16x8*)(B + b0base + k0);
    const bf16x8 b10 = *(const bf16x8*)(B + b1base + k0);
    const bf16x8 b01 = *(const bf16x8*)(B + b0base + k0 + 32);
    const bf16x8 b11 = *(const bf16x8*)(B + b1base + k0 + 32);
    acc0 = __builtin_amdgcn_mfma_f32_16x16x32_bf16(a0, b00, acc0, 0, 0, 0);
    acc1 = __builtin_amdgcn_mfma_f32_16x16x32_bf16(a0, b10, acc1, 0, 0, 0);
    acc0 = __builtin_amdgcn_mfma_f32_16x16x32_bf16(a1, b01, acc0, 0, 0, 0);
    acc1 = __builtin_amdgcn_mfma_f32_16x16x32_bf16(a1, b11, acc1, 0, 0, 0);
  }

  const int rbase = m * 16 + kc * 4;
  const int gc0   = n2 * 32 + r16;
#pragma unroll
  for (int j = 0; j < 4; j++) {
    const int gr = rbase + j;
    const float thr = anchor[gr] + NEGM;
    float s = 0.f;
    const float v0 = acc0[j];
    const float v1 = acc1[j];
    if (gr != gc0      && v0 <= thr) s += expf(v0 * TEMP_INV);
    if (gr != gc0 + 16 && v1 <= thr) s += expf(v1 * TEMP_INV);
    s += __shfl_xor(s, 1);
    s += __shfl_xor(s, 2);
    s += __shfl_xor(s, 4);
    s += __shfl_xor(s, 8);
    if (r16 == 0) atomicAdd(neg + gr, s);
  }
}

// ---- k_loss: per-b loss, mean ------------------------------------------------
__global__ __launch_bounds__(512) void k_loss(const float* __restrict__ pos,
                                              const float* __restrict__ neg,
                                              float* __restrict__ out) {
  const int t = threadIdx.x;
  const float p = pos[t];
  const float n = neg[t];
  float l = -logf(p / (p + n + 1e-8f));
#pragma unroll
  for (int off = 32; off > 0; off >>= 1) l += __shfl_down(l, off);
  __shared__ float s[8];
  if ((t & 63) == 0) s[t >> 6] = l;
  __syncthreads();
  if (t == 0) {
    float tot = 0.f;
#pragma unroll
    for (int i = 0; i < 8; i++) tot += s[i];
    out[0] = tot / (float)NB;
  }
}

extern "C" void kernel_launch(void* const* d_in, const int* in_sizes, int n_in,
                              void* d_out, int out_size, void* d_ws, size_t ws_size,
                              hipStream_t stream) {
  const float* q  = (const float*)d_in[0];
  const float* pm = (const float*)d_in[1];
  const float* ph = (const float*)d_in[2];
  const float* nm = (const float*)d_in[3];
  const float* nh = (const float*)d_in[4];
  float* out = (float*)d_out;

  float* ws = (float*)d_ws;
  float*          qn     = ws;                                  // 512*2048 f32 (4 MB)
  unsigned short* qb     = (unsigned short*)(ws + (size_t)NB * ND);        // 2 MB
  unsigned short* pb     = qb + (size_t)NB * ND;                           // 2 MB
  float*          anchor = (float*)(pb + (size_t)NB * ND);      // 512
  float*          pos    = anchor + NB;                         // 512
  float*          neg    = pos + NB;                            // 512

  k_prep<<<NB, 256, 0, stream>>>(q, pm, qn, qb, pb, anchor, pos, neg);
  k_rows<<<NROWS / 4, 256, 0, stream>>>(pm, ph, nm, nh, qn, anchor, pos, neg);
  k_sim<<<dim3(128, 1, 3), 256, 0, stream>>>(qb, pb, anchor, neg);
  k_loss<<<1, 512, 0, stream>>>(pos, neg, out);
}

// Round 3
// 244.374 us; speedup vs baseline: 1.9139x; 1.0152x over previous
//
#include <hip/hip_runtime.h>
#include <math.h>

#define NB   512
#define NPM  8
#define NPH  16
#define NNM  64
#define NNH  64
#define ND   2048
#define TEMP_INV 14.285714285714285714f
#define POSM 0.1f
#define NEGM 0.1f

static constexpr int ROWS_PER_B = NPM + NPH + NNM + NNH;  // 152
static constexpr int NROWS      = NB * ROWS_PER_B;        // 77824

typedef __attribute__((ext_vector_type(8))) short bf16x8;
typedef __attribute__((ext_vector_type(4))) float f32x4;

// round-to-nearest-even f32 -> bf16 bits (inputs are normal floats)
__device__ __forceinline__ unsigned short f2bf(float f) {
  unsigned int u = __float_as_uint(f);
  return (unsigned short)((u + 0x7FFFu + ((u >> 16) & 1u)) >> 16);
}

__device__ __forceinline__ void acc_ss_dot(const float4 v, const float4 u,
                                           float& ss, float& dot) {
  ss  = fmaf(v.x, v.x, ss);  ss  = fmaf(v.y, v.y, ss);
  ss  = fmaf(v.z, v.z, ss);  ss  = fmaf(v.w, v.w, ss);
  dot = fmaf(v.x, u.x, dot); dot = fmaf(v.y, u.y, dot);
  dot = fmaf(v.z, u.z, dot); dot = fmaf(v.w, u.w, dot);
}

__device__ __forceinline__ void block_reduce2(float& a, float& b) {
#pragma unroll
  for (int off = 32; off > 0; off >>= 1) {
    a += __shfl_down(a, off);
    b += __shfl_down(b, off);
  }
  __shared__ float sa[4], sb[4];
  const int w = threadIdx.x >> 6;
  if ((threadIdx.x & 63) == 0) { sa[w] = a; sb[w] = b; }
  __syncthreads();
  a = sa[0] + sa[1] + sa[2] + sa[3];
  b = sb[0] + sb[1] + sb[2] + sb[3];
  __syncthreads();
}

// ---- k_prep: q_norm (f32 + bf16), pf_norm (bf16), anchor, zero accumulators --
__global__ __launch_bounds__(256) void k_prep(const float* __restrict__ q,
                                              const float* __restrict__ pm,
                                              float* __restrict__ qn,
                                              unsigned short* __restrict__ qb,
                                              unsigned short* __restrict__ pb,
                                              float* __restrict__ anchor,
                                              float* __restrict__ pos,
                                              float* __restrict__ neg) {
  const int b = blockIdx.x;
  const int t = threadIdx.x;

  const float4* qrow = (const float4*)(q + (size_t)b * ND);
  float4 q0 = qrow[t];
  float4 q1 = qrow[t + 256];
  float ss = 0.f, dummy = 0.f;
  ss = fmaf(q0.x, q0.x, ss); ss = fmaf(q0.y, q0.y, ss);
  ss = fmaf(q0.z, q0.z, ss); ss = fmaf(q0.w, q0.w, ss);
  ss = fmaf(q1.x, q1.x, ss); ss = fmaf(q1.y, q1.y, ss);
  ss = fmaf(q1.z, q1.z, ss); ss = fmaf(q1.w, q1.w, ss);
  block_reduce2(ss, dummy);
  const float qinv = 1.0f / fmaxf(sqrtf(ss), 1e-8f);
  q0.x *= qinv; q0.y *= qinv; q0.z *= qinv; q0.w *= qinv;
  q1.x *= qinv; q1.y *= qinv; q1.z *= qinv; q1.w *= qinv;
  float4* qno = (float4*)(qn + (size_t)b * ND);
  qno[t] = q0; qno[t + 256] = q1;
  ushort4* qbo = (ushort4*)(qb + (size_t)b * ND);
  ushort4 qc0, qc1;
  qc0.x = f2bf(q0.x); qc0.y = f2bf(q0.y); qc0.z = f2bf(q0.z); qc0.w = f2bf(q0.w);
  qc1.x = f2bf(q1.x); qc1.y = f2bf(q1.y); qc1.z = f2bf(q1.z); qc1.w = f2bf(q1.w);
  qbo[t] = qc0; qbo[t + 256] = qc1;

  const float4* prow = (const float4*)(pm + (size_t)b * NPM * ND);
  float4 p0 = prow[t];
  float4 p1 = prow[t + 256];
  float pss = 0.f, dot = 0.f;
  acc_ss_dot(p0, q0, pss, dot);
  acc_ss_dot(p1, q1, pss, dot);
  block_reduce2(pss, dot);
  const float pinv = 1.0f / fmaxf(sqrtf(pss), 1e-8f);
  p0.x *= pinv; p0.y *= pinv; p0.z *= pinv; p0.w *= pinv;
  p1.x *= pinv; p1.y *= pinv; p1.z *= pinv; p1.w *= pinv;
  ushort4* pbo = (ushort4*)(pb + (size_t)b * ND);
  ushort4 pc0, pc1;
  pc0.x = f2bf(p0.x); pc0.y = f2bf(p0.y); pc0.z = f2bf(p0.z); pc0.w = f2bf(p0.w);
  pc1.x = f2bf(p1.x); pc1.y = f2bf(p1.y); pc1.z = f2bf(p1.z); pc1.w = f2bf(p1.w);
  pbo[t] = pc0; pbo[t + 256] = pc1;

  if (t == 0) {
    anchor[b] = dot * pinv;
    pos[b] = 0.f;
    neg[b] = 0.f;
  }
}

// ---- k_rows: one WAVE per candidate row; explicit register batching ----------
// All 8 row-float4 loads (HBM) issued first, then 8 q-float4 loads (L2), then
// the FMA chain. Arrays are statically indexed (fully unrolled) so they live
// in VGPRs -> ~16 loads in flight per wave -> HBM-BW-bound, not latency-bound.
__global__ __launch_bounds__(256) void k_rows(const float* __restrict__ pmain,
                                              const float* __restrict__ phard,
                                              const float* __restrict__ nmain,
                                              const float* __restrict__ nhard,
                                              const float* __restrict__ qn,
                                              const float* __restrict__ anchor,
                                              float* __restrict__ pos,
                                              float* __restrict__ neg) {
  const int w = blockIdx.x * 4 + (threadIdx.x >> 6);  // row id, < 77824
  const int lane = threadIdx.x & 63;
  const int b = w / ROWS_PER_B;
  const int r = w % ROWS_PER_B;

  const float* base;
  int kind;  // 0 = pos_main (unmasked), 1 = pos_hard, 2 = negative
  if (r < NPM) {
    base = pmain + ((size_t)b * NPM + r) * ND; kind = 0;
  } else if (r < NPM + NPH) {
    base = phard + ((size_t)b * NPH + (r - NPM)) * ND; kind = 1;
  } else if (r < NPM + NPH + NNM) {
    base = nmain + ((size_t)b * NNM + (r - NPM - NPH)) * ND; kind = 2;
  } else {
    base = nhard + ((size_t)b * NNH + (r - NPM - NPH - NNM)) * ND; kind = 2;
  }

  const float4* row  = (const float4*)base;
  const float4* qrow = (const float4*)(qn + (size_t)b * ND);

  float4 v[8], u[8];
#pragma unroll
  for (int j = 0; j < 8; j++) v[j] = row[lane + 64 * j];    // HBM stream first
#pragma unroll
  for (int j = 0; j < 8; j++) u[j] = qrow[lane + 64 * j];   // L2-resident
  float ss = 0.f, dot = 0.f;
#pragma unroll
  for (int j = 0; j < 8; j++) acc_ss_dot(v[j], u[j], ss, dot);

#pragma unroll
  for (int off = 32; off > 0; off >>= 1) {
    ss  += __shfl_xor(ss, off);
    dot += __shfl_xor(dot, off);
  }

  if (lane == 0) {
    const float sim = dot / fmaxf(sqrtf(ss), 1e-8f);
    const float a   = anchor[b];
    const float e   = expf(sim * TEMP_INV);
    if (kind == 0) {
      atomicAdd(pos + b, e);
    } else if (kind == 1) {
      if (sim >= a - POSM) atomicAdd(pos + b, e);
    } else {
      if (sim <= a + NEGM) atomicAdd(neg + b, e);
    }
  }
}

// ---- k_sim: three 512x512 sim matrices via bf16 MFMA, masked exp row-sums ----
// z=0: q@q^T, z=1: pf@pf^T, z=2: q@pf^T. One wave = 16x32 output tile.
// Fragment layout (gfx950 mfma_f32_16x16x32_bf16):
//   A/B: lane l holds row/col (l&15), k = (l>>4)*8 + j  (8 bf16 = 4 VGPRs)
//   C/D: col = lane&15, row = (lane>>4)*4 + reg          [m89-verified]
__global__ __launch_bounds__(256) void k_sim(const unsigned short* __restrict__ qb,
                                             const unsigned short* __restrict__ pb,
                                             const float* __restrict__ anchor,
                                             float* __restrict__ neg) {
  const int z = blockIdx.z;
  const unsigned short* __restrict__ A = (z == 1) ? pb : qb;
  const unsigned short* __restrict__ B = (z == 0) ? qb : pb;

  const int wid  = blockIdx.x * 4 + (threadIdx.x >> 6);  // 0..511
  const int m    = wid >> 4;   // row-tile 0..31
  const int n2   = wid & 15;   // col-pair 0..15
  const int lane = threadIdx.x & 63;
  const int r16  = lane & 15;
  const int kc   = lane >> 4;

  const size_t abase  = ((size_t)(m * 16 + r16)) * ND + kc * 8;
  const size_t b0base = ((size_t)(n2 * 32 + r16)) * ND + kc * 8;
  const size_t b1base = b0base + (size_t)16 * ND;

  f32x4 acc0 = {0.f, 0.f, 0.f, 0.f};
  f32x4 acc1 = {0.f, 0.f, 0.f, 0.f};
#pragma unroll 2
  for (int k0 = 0; k0 < ND; k0 += 64) {
    const bf16x8 a0  = *(const bf16x8*)(A + abase  + k0);
    const bf16x8 a1  = *(const bf16x8*)(A + abase  + k0 + 32);
    const bf16x8 b00 = *(const bf16x8*)(B + b0base + k0);
    const bf16x8 b10 = *(const bf16x8*)(B + b1base + k0);
    const bf16x8 b01 = *(const bf16x8*)(B + b0base + k0 + 32);
    const bf16x8 b11 = *(const bf16x8*)(B + b1base + k0 + 32);
    acc0 = __builtin_amdgcn_mfma_f32_16x16x32_bf16(a0, b00, acc0, 0, 0, 0);
    acc1 = __builtin_amdgcn_mfma_f32_16x16x32_bf16(a0, b10, acc1, 0, 0, 0);
    acc0 = __builtin_amdgcn_mfma_f32_16x16x32_bf16(a1, b01, acc0, 0, 0, 0);
    acc1 = __builtin_amdgcn_mfma_f32_16x16x32_bf16(a1, b11, acc1, 0, 0, 0);
  }

  const int rbase = m * 16 + kc * 4;
  const int gc0   = n2 * 32 + r16;
#pragma unroll
  for (int j = 0; j < 4; j++) {
    const int gr = rbase + j;
    const float thr = anchor[gr] + NEGM;
    float s = 0.f;
    const float v0 = acc0[j];
    const float v1 = acc1[j];
    if (gr != gc0      && v0 <= thr) s += expf(v0 * TEMP_INV);
    if (gr != gc0 + 16 && v1 <= thr) s += expf(v1 * TEMP_INV);
    s += __shfl_xor(s, 1);
    s += __shfl_xor(s, 2);
    s += __shfl_xor(s, 4);
    s += __shfl_xor(s, 8);
    if (r16 == 0) atomicAdd(neg + gr, s);
  }
}

// ---- k_loss: per-b loss, mean ------------------------------------------------
__global__ __launch_bounds__(512) void k_loss(const float* __restrict__ pos,
                                              const float* __restrict__ neg,
                                              float* __restrict__ out) {
  const int t = threadIdx.x;
  const float p = pos[t];
  const float n = neg[t];
  float l = -logf(p / (p + n + 1e-8f));
#pragma unroll
  for (int off = 32; off > 0; off >>= 1) l += __shfl_down(l, off);
  __shared__ float s[8];
  if ((t & 63) == 0) s[t >> 6] = l;
  __syncthreads();
  if (t == 0) {
    float tot = 0.f;
#pragma unroll
    for (int i = 0; i < 8; i++) tot += s[i];
    out[0] = tot / (float)NB;
  }
}

extern "C" void kernel_launch(void* const* d_in, const int* in_sizes, int n_in,
                              void* d_out, int out_size, void* d_ws, size_t ws_size,
                              hipStream_t stream) {
  const float* q  = (const float*)d_in[0];
  const float* pm = (const float*)d_in[1];
  const float* ph = (const float*)d_in[2];
  const float* nm = (const float*)d_in[3];
  const float* nh = (const float*)d_in[4];
  float* out = (float*)d_out;

  float* ws = (float*)d_ws;
  float*          qn     = ws;                                  // 512*2048 f32 (4 MB)
  unsigned short* qb     = (unsigned short*)(ws + (size_t)NB * ND);        // 2 MB
  unsigned short* pb     = qb + (size_t)NB * ND;                           // 2 MB
  float*          anchor = (float*)(pb + (size_t)NB * ND);      // 512
  float*          pos    = anchor + NB;                         // 512
  float*          neg    = pos + NB;                            // 512

  k_prep<<<NB, 256, 0, stream>>>(q, pm, qn, qb, pb, anchor, pos, neg);
  k_rows<<<NROWS / 4, 256, 0, stream>>>(pm, ph, nm, nh, qn, anchor, pos, neg);
  k_sim<<<dim3(128, 1, 3), 256, 0, stream>>>(qb, pb, anchor, neg);
  k_loss<<<1, 512, 0, stream>>>(pos, neg, out);
}

// Round 4
// 192.860 us; speedup vs baseline: 2.4251x; 1.2671x over previous
//
#include <hip/hip_runtime.h>
#include <math.h>

#define NB   512
#define NPM  8
#define NPH  16
#define NNM  64
#define NNH  64
#define ND   2048
#define TEMP_INV 14.285714285714285714f
#define POSM 0.1f
#define NEGM 0.1f

static constexpr int ROWS_PER_B = NPM + NPH + NNM + NNH;  // 152
static constexpr int WPB        = 16;                     // waves per b

typedef __attribute__((ext_vector_type(8))) short bf16x8;
typedef __attribute__((ext_vector_type(4))) float f32x4;

// round-to-nearest-even f32 -> bf16 bits
__device__ __forceinline__ unsigned short f2bf(float f) {
  unsigned int u = __float_as_uint(f);
  return (unsigned short)((u + 0x7FFFu + ((u >> 16) & 1u)) >> 16);
}

__device__ __forceinline__ void acc_ss_dot(const float4 v, const float4 u,
                                           float& ss, float& dot) {
  ss  = fmaf(v.x, v.x, ss);  ss  = fmaf(v.y, v.y, ss);
  ss  = fmaf(v.z, v.z, ss);  ss  = fmaf(v.w, v.w, ss);
  dot = fmaf(v.x, u.x, dot); dot = fmaf(v.y, u.y, dot);
  dot = fmaf(v.z, u.z, dot); dot = fmaf(v.w, u.w, dot);
}

__device__ __forceinline__ void block_reduce2(float& a, float& b) {
#pragma unroll
  for (int off = 32; off > 0; off >>= 1) {
    a += __shfl_down(a, off);
    b += __shfl_down(b, off);
  }
  __shared__ float sa[4], sb[4];
  const int w = threadIdx.x >> 6;
  if ((threadIdx.x & 63) == 0) { sa[w] = a; sb[w] = b; }
  __syncthreads();
  a = sa[0] + sa[1] + sa[2] + sa[3];
  b = sb[0] + sb[1] + sb[2] + sb[3];
  __syncthreads();
}

// ---- k_prep: q_norm (f32 + bf16), pf_norm (bf16), anchor, zero accumulators --
__global__ __launch_bounds__(256) void k_prep(const float* __restrict__ q,
                                              const float* __restrict__ pm,
                                              float* __restrict__ qn,
                                              unsigned short* __restrict__ qb,
                                              unsigned short* __restrict__ pb,
                                              float* __restrict__ anchor,
                                              float* __restrict__ pos,
                                              float* __restrict__ neg) {
  const int b = blockIdx.x;
  const int t = threadIdx.x;

  const float4* qrow = (const float4*)(q + (size_t)b * ND);
  float4 q0 = qrow[t];
  float4 q1 = qrow[t + 256];
  float ss = 0.f, dummy = 0.f;
  ss = fmaf(q0.x, q0.x, ss); ss = fmaf(q0.y, q0.y, ss);
  ss = fmaf(q0.z, q0.z, ss); ss = fmaf(q0.w, q0.w, ss);
  ss = fmaf(q1.x, q1.x, ss); ss = fmaf(q1.y, q1.y, ss);
  ss = fmaf(q1.z, q1.z, ss); ss = fmaf(q1.w, q1.w, ss);
  block_reduce2(ss, dummy);
  const float qinv = 1.0f / fmaxf(sqrtf(ss), 1e-8f);
  q0.x *= qinv; q0.y *= qinv; q0.z *= qinv; q0.w *= qinv;
  q1.x *= qinv; q1.y *= qinv; q1.z *= qinv; q1.w *= qinv;
  float4* qno = (float4*)(qn + (size_t)b * ND);
  qno[t] = q0; qno[t + 256] = q1;
  ushort4* qbo = (ushort4*)(qb + (size_t)b * ND);
  ushort4 qc0, qc1;
  qc0.x = f2bf(q0.x); qc0.y = f2bf(q0.y); qc0.z = f2bf(q0.z); qc0.w = f2bf(q0.w);
  qc1.x = f2bf(q1.x); qc1.y = f2bf(q1.y); qc1.z = f2bf(q1.z); qc1.w = f2bf(q1.w);
  qbo[t] = qc0; qbo[t + 256] = qc1;

  const float4* prow = (const float4*)(pm + (size_t)b * NPM * ND);
  float4 p0 = prow[t];
  float4 p1 = prow[t + 256];
  float pss = 0.f, dot = 0.f;
  acc_ss_dot(p0, q0, pss, dot);
  acc_ss_dot(p1, q1, pss, dot);
  block_reduce2(pss, dot);
  const float pinv = 1.0f / fmaxf(sqrtf(pss), 1e-8f);
  p0.x *= pinv; p0.y *= pinv; p0.z *= pinv; p0.w *= pinv;
  p1.x *= pinv; p1.y *= pinv; p1.z *= pinv; p1.w *= pinv;
  ushort4* pbo = (ushort4*)(pb + (size_t)b * ND);
  ushort4 pc0, pc1;
  pc0.x = f2bf(p0.x); pc0.y = f2bf(p0.y); pc0.z = f2bf(p0.z); pc0.w = f2bf(p0.w);
  pc1.x = f2bf(p1.x); pc1.y = f2bf(p1.y); pc1.z = f2bf(p1.z); pc1.w = f2bf(p1.w);
  pbo[t] = pc0; pbo[t + 256] = pc1;

  if (t == 0) {
    anchor[b] = dot * pinv;
    pos[b] = 0.f;
    neg[b] = 0.f;
  }
}

// ---- k_rows: persistent waves. 16 waves per b; each wave owns rows
// wslice, wslice+16, ... (<152) of that b. q-hat held in registers across all
// of a wave's rows; one-row-deep register prefetch (ping-pong va/vb) so the
// next row's 8KB HBM stream is in flight across the current row's compute and
// reduce tail. Local pos/neg accumulation -> 2 atomics per wave.
__global__ __launch_bounds__(256) void k_rows(const float* __restrict__ pmain,
                                              const float* __restrict__ phard,
                                              const float* __restrict__ nmain,
                                              const float* __restrict__ nhard,
                                              const float* __restrict__ qn,
                                              const float* __restrict__ anchor,
                                              float* __restrict__ pos,
                                              float* __restrict__ neg) {
  const int wgl    = blockIdx.x * 4 + (threadIdx.x >> 6);  // 0..8191
  const int lane   = threadIdx.x & 63;
  const int b      = wgl >> 4;       // 0..511
  const int wslice = wgl & 15;       // 0..15

  // row r of b -> pointer into the right tensor
  auto rowp = [&](int r) -> const float4* {
    const float* p;
    if (r < NPM)                 p = pmain + ((size_t)b * NPM + r) * ND;
    else if (r < NPM + NPH)      p = phard + ((size_t)b * NPH + (r - NPM)) * ND;
    else if (r < NPM + NPH + NNM) p = nmain + ((size_t)b * NNM + (r - NPM - NPH)) * ND;
    else                          p = nhard + ((size_t)b * NNH + (r - NPM - NPH - NNM)) * ND;
    return (const float4*)p;
  };

  // hoist q-hat into registers (L2-resident read, once per wave)
  const float4* qrow = (const float4*)(qn + (size_t)b * ND);
  float4 u[8];
#pragma unroll
  for (int j = 0; j < 8; j++) u[j] = qrow[lane + 64 * j];
  const float anc = anchor[b];

  float pacc = 0.f, nacc = 0.f;
  const int n = (ROWS_PER_B - wslice + WPB - 1) / WPB;  // 9 or 10

  float4 va[8], vb[8];
  {
    const float4* p0 = rowp(wslice);
#pragma unroll
    for (int j = 0; j < 8; j++) va[j] = p0[lane + 64 * j];
  }

  // one row: prefetch row (i+1) into vnext, then compute on vcur
  auto body = [&](float4 (&vcur)[8], float4 (&vnext)[8], int i) {
    const int rn = wslice + WPB * (i + 1);
    const float4* pn = rowp(rn < ROWS_PER_B ? rn : wslice);
#pragma unroll
    for (int j = 0; j < 8; j++) vnext[j] = pn[lane + 64 * j];
    __builtin_amdgcn_sched_barrier(0);  // pin: prefetch issued before compute

    float ss = 0.f, dot = 0.f;
#pragma unroll
    for (int j = 0; j < 8; j++) acc_ss_dot(vcur[j], u[j], ss, dot);
#pragma unroll
    for (int off = 32; off > 0; off >>= 1) {
      ss  += __shfl_xor(ss, off);
      dot += __shfl_xor(dot, off);
    }
    const float sim = dot / fmaxf(sqrtf(ss), 1e-8f);
    const float e   = expf(sim * TEMP_INV);
    const int   r   = wslice + WPB * i;
    if (r < NPM) {
      pacc += e;
    } else if (r < NPM + NPH) {
      if (sim >= anc - POSM) pacc += e;
    } else {
      if (sim <= anc + NEGM) nacc += e;
    }
  };

  int i = 0;
  for (; i + 2 <= n; i += 2) {
    body(va, vb, i);
    body(vb, va, i + 1);
  }
  if (i < n) body(va, vb, i);

  if (lane == 0) {
    if (pacc != 0.f) atomicAdd(pos + b, pacc);
    if (nacc != 0.f) atomicAdd(neg + b, nacc);
  }
}

// ---- k_sim: three 512x512 sim matrices via bf16 MFMA, masked exp row-sums ----
// z=0: q@q^T, z=1: pf@pf^T, z=2: q@pf^T. One wave = 16x32 output tile.
__global__ __launch_bounds__(256) void k_sim(const unsigned short* __restrict__ qb,
                                             const unsigned short* __restrict__ pb,
                                             const float* __restrict__ anchor,
                                             float* __restrict__ neg) {
  const int z = blockIdx.z;
  const unsigned short* __restrict__ A = (z == 1) ? pb : qb;
  const unsigned short* __restrict__ B = (z == 0) ? qb : pb;

  const int wid  = blockIdx.x * 4 + (threadIdx.x >> 6);  // 0..511
  const int m    = wid >> 4;   // row-tile 0..31
  const int n2   = wid & 15;   // col-pair 0..15
  const int lane = threadIdx.x & 63;
  const int r16  = lane & 15;
  const int kc   = lane >> 4;

  const size_t abase  = ((size_t)(m * 16 + r16)) * ND + kc * 8;
  const size_t b0base = ((size_t)(n2 * 32 + r16)) * ND + kc * 8;
  const size_t b1base = b0base + (size_t)16 * ND;

  f32x4 acc0 = {0.f, 0.f, 0.f, 0.f};
  f32x4 acc1 = {0.f, 0.f, 0.f, 0.f};
#pragma unroll 2
  for (int k0 = 0; k0 < ND; k0 += 64) {
    const bf16x8 a0  = *(const bf16x8*)(A + abase  + k0);
    const bf16x8 a1  = *(const bf16x8*)(A + abase  + k0 + 32);
    const bf16x8 b00 = *(const bf16x8*)(B + b0base + k0);
    const bf16x8 b10 = *(const bf16x8*)(B + b1base + k0);
    const bf16x8 b01 = *(const bf16x8*)(B + b0base + k0 + 32);
    const bf16x8 b11 = *(const bf16x8*)(B + b1base + k0 + 32);
    acc0 = __builtin_amdgcn_mfma_f32_16x16x32_bf16(a0, b00, acc0, 0, 0, 0);
    acc1 = __builtin_amdgcn_mfma_f32_16x16x32_bf16(a0, b10, acc1, 0, 0, 0);
    acc0 = __builtin_amdgcn_mfma_f32_16x16x32_bf16(a1, b01, acc0, 0, 0, 0);
    acc1 = __builtin_amdgcn_mfma_f32_16x16x32_bf16(a1, b11, acc1, 0, 0, 0);
  }

  const int rbase = m * 16 + kc * 4;
  const int gc0   = n2 * 32 + r16;
#pragma unroll
  for (int j = 0; j < 4; j++) {
    const int gr = rbase + j;
    const float thr = anchor[gr] + NEGM;
    float s = 0.f;
    const float v0 = acc0[j];
    const float v1 = acc1[j];
    if (gr != gc0      && v0 <= thr) s += expf(v0 * TEMP_INV);
    if (gr != gc0 + 16 && v1 <= thr) s += expf(v1 * TEMP_INV);
    s += __shfl_xor(s, 1);
    s += __shfl_xor(s, 2);
    s += __shfl_xor(s, 4);
    s += __shfl_xor(s, 8);
    if (r16 == 0) atomicAdd(neg + gr, s);
  }
}

// ---- k_loss: per-b loss, mean ------------------------------------------------
__global__ __launch_bounds__(512) void k_loss(const float* __restrict__ pos,
                                              const float* __restrict__ neg,
                                              float* __restrict__ out) {
  const int t = threadIdx.x;
  const float p = pos[t];
  const float n = neg[t];
  float l = -logf(p / (p + n + 1e-8f));
#pragma unroll
  for (int off = 32; off > 0; off >>= 1) l += __shfl_down(l, off);
  __shared__ float s[8];
  if ((t & 63) == 0) s[t >> 6] = l;
  __syncthreads();
  if (t == 0) {
    float tot = 0.f;
#pragma unroll
    for (int i = 0; i < 8; i++) tot += s[i];
    out[0] = tot / (float)NB;
  }
}

extern "C" void kernel_launch(void* const* d_in, const int* in_sizes, int n_in,
                              void* d_out, int out_size, void* d_ws, size_t ws_size,
                              hipStream_t stream) {
  const float* q  = (const float*)d_in[0];
  const float* pm = (const float*)d_in[1];
  const float* ph = (const float*)d_in[2];
  const float* nm = (const float*)d_in[3];
  const float* nh = (const float*)d_in[4];
  float* out = (float*)d_out;

  float* ws = (float*)d_ws;
  float*          qn     = ws;                                  // 512*2048 f32 (4 MB)
  unsigned short* qb     = (unsigned short*)(ws + (size_t)NB * ND);        // 2 MB
  unsigned short* pb     = qb + (size_t)NB * ND;                           // 2 MB
  float*          anchor = (float*)(pb + (size_t)NB * ND);      // 512
  float*          pos    = anchor + NB;                         // 512
  float*          neg    = pos + NB;                            // 512

  k_prep<<<NB, 256, 0, stream>>>(q, pm, qn, qb, pb, anchor, pos, neg);
  k_rows<<<(NB * WPB) / 4, 256, 0, stream>>>(pm, ph, nm, nh, qn, anchor, pos, neg);
  k_sim<<<dim3(128, 1, 3), 256, 0, stream>>>(qb, pb, anchor, neg);
  k_loss<<<1, 512, 0, stream>>>(pos, neg, out);
}

// Round 7
// 171.406 us; speedup vs baseline: 2.7287x; 1.1252x over previous
//
#include <hip/hip_runtime.h>
#include <math.h>

#define NB   512
#define NPM  8
#define NPH  16
#define NNM  64
#define NNH  64
#define ND   2048
#define TEMP_INV 14.285714285714285714f
#define POSM 0.1f
#define NEGM 0.1f

static constexpr int ROWS_PER_B = NPM + NPH + NNM + NNH;  // 152
static constexpr int WPB        = 8;                      // waves per b
static constexpr int NRW        = ROWS_PER_B / WPB;       // 19 rows per wave

typedef __attribute__((ext_vector_type(8))) short bf16x8;
typedef __attribute__((ext_vector_type(4))) float f32x4;

// round-to-nearest-even f32 -> bf16 bits
__device__ __forceinline__ unsigned short f2bf(float f) {
  unsigned int u = __float_as_uint(f);
  return (unsigned short)((u + 0x7FFFu + ((u >> 16) & 1u)) >> 16);
}

__device__ __forceinline__ void acc_ss_dot(const float4 v, const float4 u,
                                           float& ss, float& dot) {
  ss  = fmaf(v.x, v.x, ss);  ss  = fmaf(v.y, v.y, ss);
  ss  = fmaf(v.z, v.z, ss);  ss  = fmaf(v.w, v.w, ss);
  dot = fmaf(v.x, u.x, dot); dot = fmaf(v.y, u.y, dot);
  dot = fmaf(v.z, u.z, dot); dot = fmaf(v.w, u.w, dot);
}

__device__ __forceinline__ void block_reduce2(float& a, float& b) {
#pragma unroll
  for (int off = 32; off > 0; off >>= 1) {
    a += __shfl_down(a, off);
    b += __shfl_down(b, off);
  }
  __shared__ float sa[4], sb[4];
  const int w = threadIdx.x >> 6;
  if ((threadIdx.x & 63) == 0) { sa[w] = a; sb[w] = b; }
  __syncthreads();
  a = sa[0] + sa[1] + sa[2] + sa[3];
  b = sb[0] + sb[1] + sb[2] + sb[3];
  __syncthreads();
}

// async global->LDS, 16 B per lane per issue (fire-and-forget, no dest VGPRs)
__device__ __forceinline__ void gl_lds16(const float* g, float* l) {
  __builtin_amdgcn_global_load_lds(
      (const __attribute__((address_space(1))) unsigned int*)g,
      (__attribute__((address_space(3))) unsigned int*)l, 16, 0, 0);
}

// ---- k_prep: q_norm (f32 + bf16), pf_norm (bf16), anchor, zero accumulators --
__global__ __launch_bounds__(256) void k_prep(const float* __restrict__ q,
                                              const float* __restrict__ pm,
                                              float* __restrict__ qn,
                                              unsigned short* __restrict__ qb,
                                              unsigned short* __restrict__ pb,
                                              float* __restrict__ anchor,
                                              float* __restrict__ pos,
                                              float* __restrict__ neg) {
  const int b = blockIdx.x;
  const int t = threadIdx.x;

  const float4* qrow = (const float4*)(q + (size_t)b * ND);
  float4 q0 = qrow[t];
  float4 q1 = qrow[t + 256];
  float ss = 0.f, dummy = 0.f;
  ss = fmaf(q0.x, q0.x, ss); ss = fmaf(q0.y, q0.y, ss);
  ss = fmaf(q0.z, q0.z, ss); ss = fmaf(q0.w, q0.w, ss);
  ss = fmaf(q1.x, q1.x, ss); ss = fmaf(q1.y, q1.y, ss);
  ss = fmaf(q1.z, q1.z, ss); ss = fmaf(q1.w, q1.w, ss);
  block_reduce2(ss, dummy);
  const float qinv = 1.0f / fmaxf(sqrtf(ss), 1e-8f);
  q0.x *= qinv; q0.y *= qinv; q0.z *= qinv; q0.w *= qinv;
  q1.x *= qinv; q1.y *= qinv; q1.z *= qinv; q1.w *= qinv;
  float4* qno = (float4*)(qn + (size_t)b * ND);
  qno[t] = q0; qno[t + 256] = q1;
  ushort4* qbo = (ushort4*)(qb + (size_t)b * ND);
  ushort4 qc0, qc1;
  qc0.x = f2bf(q0.x); qc0.y = f2bf(q0.y); qc0.z = f2bf(q0.z); qc0.w = f2bf(q0.w);
  qc1.x = f2bf(q1.x); qc1.y = f2bf(q1.y); qc1.z = f2bf(q1.z); qc1.w = f2bf(q1.w);
  qbo[t] = qc0; qbo[t + 256] = qc1;

  const float4* prow = (const float4*)(pm + (size_t)b * NPM * ND);
  float4 p0 = prow[t];
  float4 p1 = prow[t + 256];
  float pss = 0.f, dot = 0.f;
  acc_ss_dot(p0, q0, pss, dot);
  acc_ss_dot(p1, q1, pss, dot);
  block_reduce2(pss, dot);
  const float pinv = 1.0f / fmaxf(sqrtf(pss), 1e-8f);
  p0.x *= pinv; p0.y *= pinv; p0.z *= pinv; p0.w *= pinv;
  p1.x *= pinv; p1.y *= pinv; p1.z *= pinv; p1.w *= pinv;
  ushort4* pbo = (ushort4*)(pb + (size_t)b * ND);
  ushort4 pc0, pc1;
  pc0.x = f2bf(p0.x); pc0.y = f2bf(p0.y); pc0.z = f2bf(p0.z); pc0.w = f2bf(p0.w);
  pc1.x = f2bf(p1.x); pc1.y = f2bf(p1.y); pc1.z = f2bf(p1.z); pc1.w = f2bf(p1.w);
  pbo[t] = pc0; pbo[t + 256] = pc1;

  if (t == 0) {
    anchor[b] = dot * pinv;
    pos[b] = 0.f;
    neg[b] = 0.f;
  }
}

// ---- k_rows: persistent waves; global_load_lds double-buffered row stream ----
// WPB=8 -> every wave handles exactly 19 rows (w, w+8, ..., w+144) of its b.
// Each wave owns a PRIVATE 2 x 8KB LDS slot: no __syncthreads anywhere, so no
// barrier-drain. Counted s_waitcnt vmcnt(8) keeps the next row's 8 DMA loads
// in flight across the current row's compute; vmcnt(0) only in the epilogue.
__global__ __launch_bounds__(256) void k_rows(const float* __restrict__ pmain,
                                              const float* __restrict__ phard,
                                              const float* __restrict__ nmain,
                                              const float* __restrict__ nhard,
                                              const float* __restrict__ qn,
                                              const float* __restrict__ anchor,
                                              float* __restrict__ pos,
                                              float* __restrict__ neg) {
  __shared__ float lds[4][2][ND];  // 64 KB: [wave][buf][row]

  const int wid    = threadIdx.x >> 6;
  const int lane   = threadIdx.x & 63;
  const int wgl    = blockIdx.x * 4 + wid;   // 0..4095
  const int b      = wgl >> 3;               // 0..511
  const int wslice = wgl & 7;                // 0..7

  // row k (0..18) -> per-lane global base pointer (row index wslice + 8k)
  auto rowp = [&](int k) -> const float* {
    const int r = wslice + WPB * k;          // < 152 always
    const float* p;
    if (r < NPM)                  p = pmain + ((size_t)b * NPM + r) * ND;
    else if (r < NPM + NPH)       p = phard + ((size_t)b * NPH + (r - NPM)) * ND;
    else if (r < NPM + NPH + NNM) p = nmain + ((size_t)b * NNM + (r - NPM - NPH)) * ND;
    else                          p = nhard + ((size_t)b * NNH + (r - NPM - NPH - NNM)) * ND;
    return p + lane * 4;
  };

  // stage one row (8 KB) into an LDS slot: 8 async DMA issues of 1 KB
  auto stage = [&](int k, float* slot) {
#pragma unroll
    for (int c = 0; c < 8; c++) gl_lds16(rowp(k) + c * 256, slot + c * 256);
  };

  // q-hat hoisted to registers (L2-resident, once per wave)
  const float4* qrow = (const float4*)(qn + (size_t)b * ND);
  float4 u[8];
#pragma unroll
  for (int j = 0; j < 8; j++) u[j] = qrow[lane + 64 * j];
  const float anc = anchor[b];

  float pacc = 0.f, nacc = 0.f;

  // consume one staged row from LDS
  auto process = [&](const float* slot, int k) {
    const float4* lb = (const float4*)slot;
    float ss0 = 0.f, ss1 = 0.f, d0 = 0.f, d1 = 0.f;
#pragma unroll
    for (int j = 0; j < 8; j += 2) {
      const float4 v0 = lb[lane + 64 * j];
      const float4 v1 = lb[lane + 64 * (j + 1)];
      acc_ss_dot(v0, u[j], ss0, d0);
      acc_ss_dot(v1, u[j + 1], ss1, d1);
    }
    float ss = ss0 + ss1, dt = d0 + d1;
#pragma unroll
    for (int off = 32; off > 0; off >>= 1) {
      ss += __shfl_xor(ss, off);
      dt += __shfl_xor(dt, off);
    }
    const float sim = dt * rsqrtf(fmaxf(ss, 1e-16f));
    const float e   = __expf(sim * TEMP_INV);
    const int   r   = wslice + WPB * k;
    if (r < NPM) {
      pacc += e;
    } else if (r < NPM + NPH) {
      if (sim >= anc - POSM) pacc += e;
    } else {
      if (sim <= anc + NEGM) nacc += e;
    }
  };

  float* cur = &lds[wid][0][0];
  float* nxt = &lds[wid][1][0];

  stage(0, cur);
  for (int k = 0; k + 1 < NRW; ++k) {
    stage(k + 1, nxt);
    asm volatile("s_waitcnt vmcnt(8)" ::: "memory");  // cur ready, nxt in flight
    __builtin_amdgcn_sched_barrier(0);
    process(cur, k);
    float* t = cur; cur = nxt; nxt = t;
  }
  asm volatile("s_waitcnt vmcnt(0)" ::: "memory");    // full drain before exit
  __builtin_amdgcn_sched_barrier(0);
  process(cur, NRW - 1);

  if (lane == 0) {
    if (pacc != 0.f) atomicAdd(pos + b, pacc);
    if (nacc != 0.f) atomicAdd(neg + b, nacc);
  }
}

// ---- k_sim: three 512x512 sim matrices via bf16 MFMA, masked exp row-sums ----
__global__ __launch_bounds__(256) void k_sim(const unsigned short* __restrict__ qb,
                                             const unsigned short* __restrict__ pb,
                                             const float* __restrict__ anchor,
                                             float* __restrict__ neg) {
  const int z = blockIdx.z;
  const unsigned short* __restrict__ A = (z == 1) ? pb : qb;
  const unsigned short* __restrict__ B = (z == 0) ? qb : pb;

  const int wid  = blockIdx.x * 4 + (threadIdx.x >> 6);  // 0..511
  const int m    = wid >> 4;   // row-tile 0..31
  const int n2   = wid & 15;   // col-pair 0..15
  const int lane = threadIdx.x & 63;
  const int r16  = lane & 15;
  const int kc   = lane >> 4;

  const size_t abase  = ((size_t)(m * 16 + r16)) * ND + kc * 8;
  const size_t b0base = ((size_t)(n2 * 32 + r16)) * ND + kc * 8;
  const size_t b1base = b0base + (size_t)16 * ND;

  f32x4 acc0 = {0.f, 0.f, 0.f, 0.f};
  f32x4 acc1 = {0.f, 0.f, 0.f, 0.f};
#pragma unroll 2
  for (int k0 = 0; k0 < ND; k0 += 64) {
    const bf16x8 a0  = *(const bf16x8*)(A + abase  + k0);
    const bf16x8 a1  = *(const bf16x8*)(A + abase  + k0 + 32);
    const bf16x8 b00 = *(const bf16x8*)(B + b0base + k0);
    const bf16x8 b10 = *(const bf16x8*)(B + b1base + k0);
    const bf16x8 b01 = *(const bf16x8*)(B + b0base + k0 + 32);
    const bf16x8 b11 = *(const bf16x8*)(B + b1base + k0 + 32);
    acc0 = __builtin_amdgcn_mfma_f32_16x16x32_bf16(a0, b00, acc0, 0, 0, 0);
    acc1 = __builtin_amdgcn_mfma_f32_16x16x32_bf16(a0, b10, acc1, 0, 0, 0);
    acc0 = __builtin_amdgcn_mfma_f32_16x16x32_bf16(a1, b01, acc0, 0, 0, 0);
    acc1 = __builtin_amdgcn_mfma_f32_16x16x32_bf16(a1, b11, acc1, 0, 0, 0);
  }

  const int rbase = m * 16 + kc * 4;
  const int gc0   = n2 * 32 + r16;
#pragma unroll
  for (int j = 0; j < 4; j++) {
    const int gr = rbase + j;
    const float thr = anchor[gr] + NEGM;
    float s = 0.f;
    const float v0 = acc0[j];
    const float v1 = acc1[j];
    if (gr != gc0      && v0 <= thr) s += expf(v0 * TEMP_INV);
    if (gr != gc0 + 16 && v1 <= thr) s += expf(v1 * TEMP_INV);
    s += __shfl_xor(s, 1);
    s += __shfl_xor(s, 2);
    s += __shfl_xor(s, 4);
    s += __shfl_xor(s, 8);
    if (r16 == 0) atomicAdd(neg + gr, s);
  }
}

// ---- k_loss: per-b loss, mean ------------------------------------------------
__global__ __launch_bounds__(512) void k_loss(const float* __restrict__ pos,
                                              const float* __restrict__ neg,
                                              float* __restrict__ out) {
  const int t = threadIdx.x;
  const float p = pos[t];
  const float n = neg[t];
  float l = -logf(p / (p + n + 1e-8f));
#pragma unroll
  for (int off = 32; off > 0; off >>= 1) l += __shfl_down(l, off);
  __shared__ float s[8];
  if ((t & 63) == 0) s[t >> 6] = l;
  __syncthreads();
  if (t == 0) {
    float tot = 0.f;
#pragma unroll
    for (int i = 0; i < 8; i++) tot += s[i];
    out[0] = tot / (float)NB;
  }
}

extern "C" void kernel_launch(void* const* d_in, const int* in_sizes, int n_in,
                              void* d_out, int out_size, void* d_ws, size_t ws_size,
                              hipStream_t stream) {
  const float* q  = (const float*)d_in[0];
  const float* pm = (const float*)d_in[1];
  const float* ph = (const float*)d_in[2];
  const float* nm = (const float*)d_in[3];
  const float* nh = (const float*)d_in[4];
  float* out = (float*)d_out;

  float* ws = (float*)d_ws;
  float*          qn     = ws;                                  // 512*2048 f32 (4 MB)
  unsigned short* qb     = (unsigned short*)(ws + (size_t)NB * ND);        // 2 MB
  unsigned short* pb     = qb + (size_t)NB * ND;                           // 2 MB
  float*          anchor = (float*)(pb + (size_t)NB * ND);      // 512
  float*          pos    = anchor + NB;                         // 512
  float*          neg    = pos + NB;                            // 512

  k_prep<<<NB, 256, 0, stream>>>(q, pm, qn, qb, pb, anchor, pos, neg);
  k_rows<<<(NB * WPB) / 4, 256, 0, stream>>>(pm, ph, nm, nh, qn, anchor, pos, neg);
  k_sim<<<dim3(128, 1, 3), 256, 0, stream>>>(qb, pb, anchor, neg);
  k_loss<<<1, 512, 0, stream>>>(pos, neg, out);
}